// Round 9
// baseline (468.486 us; speedup 1.0000x reference)
//
#include <hip/hip_runtime.h>

// SNN forward, round 9.
// convT: r3 skeleton, but 512-thr blocks x 2 blocks/CU = 4 waves/SIMD (TLP
// theory: per-wave MFMA serialization means util scales with waves/SIMD, not
// in-wave acc count). Wave = (hl, ct, jp): 3 accs (48 reg), no dummy tiles
// (MFMA/item 1536 -> 1152). Per round/wave: 1 global A + 3 ds_read + 3 MFMA.
// u_hi/u_lo planes folded in LIF (per-acc accumulation order unchanged).

typedef __attribute__((ext_vector_type(8))) _Float16 v8h;
typedef __attribute__((ext_vector_type(16))) float v16f;
typedef _Float16 half_t;

#define NB 32
#define NC 64
#define NT 129
#define TIN 128
#define NM 40
#define MSTR 136          // LDS per-slot stride: conflict-free (0 conflicts measured)
#define SROWB 5120        // global spike row bytes = 40*64*2

// ---- weights -> MFMA A-fragments, order [tap12][cq4][ct2][hl2][lane64]x16B ----
// A-frag (32x32x16 f16): lane holds A[co=ct*32+(lane&31)][ci=cq*16+(lane>>5)*8+jj]
__global__ void prep_wfrag2(const float* __restrict__ w2, const float* __restrict__ w3,
                            uint4* __restrict__ wfA, uint4* __restrict__ wfB) {
    int tid = blockIdx.x * 256 + threadIdx.x;   // 24576
    if (tid >= 24576) return;
    const float* w = (tid < 12288) ? w2 : w3;
    uint4* wf = (tid < 12288) ? wfA : wfB;
    int t2 = (tid < 12288) ? tid : tid - 12288;
    int lane = t2 & 63;
    int rest = t2 >> 6;
    int hl = rest & 1;
    int ct = (rest >> 1) & 1;
    int cq = (rest >> 2) & 3;
    int tap = rest >> 4;
    int kh = tap / 3, kw = tap % 3;
    int co = ct * 32 + (lane & 31);
    unsigned short o[8];
#pragma unroll
    for (int jj = 0; jj < 8; jj++) {
        int ci = cq * 16 + (lane >> 5) * 8 + jj;
        float wv = w[((co * 64 + ci) * 4 + kh) * 3 + kw];
        _Float16 hi = (_Float16)wv;
        _Float16 val = hl ? (_Float16)((wv - (float)hi) * 2048.0f) : hi;
        unsigned short us;
        __builtin_memcpy(&us, &val, 2);
        o[jj] = us;
    }
    uint4 r;
    __builtin_memcpy(&r, o, 16);
    wf[t2] = r;
}

// ---- conv1 (1->64ch, 4x3, pad(2,1)) + LIF1, unroll-8 row prefetch ----
__global__ void conv1_lif1(const float* __restrict__ x, const float* __restrict__ w1,
                           half_t* __restrict__ s1) {
    const int mg = blockIdx.x;        // 0..9
    const int b = blockIdx.y;
    const int c = threadIdx.x & 63;
    const int ml = threadIdx.x >> 6;  // 0..3
    const int m = mg * 4 + ml;
    float w[4][3];
#pragma unroll
    for (int kh = 0; kh < 4; kh++)
#pragma unroll
        for (int kw = 0; kw < 3; kw++) w[kh][kw] = w1[(c * 4 + kh) * 3 + kw];
    const float* xb = x + (size_t)b * TIN * NM;

    float xw[12][3];
#pragma unroll
    for (int rr = 0; rr < 12; rr++)
#pragma unroll
        for (int kw = 0; kw < 3; kw++) xw[rr][kw] = 0.f;
#pragma unroll
    for (int rr = 2; rr < 4; rr++)
#pragma unroll
        for (int kw = 0; kw < 3; kw++) {
            int mc = m - 1 + kw;
            xw[rr][kw] = ((unsigned)mc < (unsigned)NM) ? xb[(rr - 2) * NM + mc] : 0.f;
        }

    half_t* orow = s1 + ((size_t)b * NT * NM + m) * 64 + c;
    float v = 0.f;
    const float TAUc = 10.0f / 7.0f;

    for (int tb = 0; tb < NT; tb += 8) {
#pragma unroll
        for (int q = 0; q < 8; q++) {
            int row = tb + 2 + q;
#pragma unroll
            for (int kw = 0; kw < 3; kw++) {
                int mc = m - 1 + kw;
                xw[4 + q][kw] = (row < TIN && (unsigned)mc < (unsigned)NM)
                                    ? xb[row * NM + mc] : 0.f;
            }
        }
        int kmax = (NT - tb) < 8 ? (NT - tb) : 8;
#pragma unroll
        for (int k = 0; k < 8; k++) {
            if (k < kmax) {
                float uacc = 0.f;
#pragma unroll
                for (int kh = 0; kh < 4; kh++)
#pragma unroll
                    for (int kw = 0; kw < 3; kw++) uacc += xw[k + kh][kw] * w[kh][kw];
                v = v + (uacc - v) / TAUc;
                float s = (v >= 1.0f) ? 1.0f : 0.0f;
                orow[(size_t)(tb + k) * NM * 64] = (half_t)s;
                if (v >= 1.0f) v = 0.0f;
            }
        }
#pragma unroll
        for (int rr = 0; rr < 4; rr++)
#pragma unroll
            for (int kw = 0; kw < 3; kw++) xw[rr][kw] = xw[8 + rr][kw];
    }
}

// ---- MFMA conv 64->64, 4x3 dilated; 512 thr, 4 waves/SIMD ----
// grid (33, 32). bx<32: r = bx%RMOD, j0 = (bx>>RSH)*4; bx==32: r=0, j0=(32>>RSH)*4.
// Wave w (0..7): hl = w&1, ct = (w>>1)&1, jp = w>>2; 3 m-tile accs.
template <int DH, int PH, int DW, int PW, int EXT, int RSH, int NSTG>
__global__ __launch_bounds__(512, 4) void convT(const half_t* __restrict__ spk,
                                                const uint4* __restrict__ wfrag,
                                                float* __restrict__ u_hi,
                                                float* __restrict__ u_lo) {
    extern __shared__ char lds[];
    constexpr int LROWB = EXT * MSTR;
    constexpr int NCH = 7 * EXT * 8;            // 16B staging chunks
    const int tid = threadIdx.x;
    const int lane = tid & 63;
    const int wv = tid >> 6;                    // 0..7
    const int bx = blockIdx.x;                  // 0..32
    const int b = blockIdx.y;
    int r, q;
    if (bx < 32) { r = bx & ((1 << RSH) - 1); q = bx >> RSH; }
    else         { r = 0; q = 32 >> RSH; }
    const int j0 = 4 * q;

    // ---- stage 7 spike lattice rows (zero-fill OOB), one barrier ----
    const char* spb = (const char*)spk + (size_t)b * NT * SROWB;
#pragma unroll
    for (int k = 0; k < NSTG; k++) {
        int c = tid + k * 512;
        if (c < NCH) {
            int i = c / (EXT * 8);
            int rem = c - i * (EXT * 8);
            int s = rem >> 3;
            int ci8 = rem & 7;
            int tg = r - PH + DH * (j0 + i);
            int md = s - PW;
            uint4 val = make_uint4(0u, 0u, 0u, 0u);
            if ((unsigned)tg < (unsigned)NT && (unsigned)md < (unsigned)NM)
                val = *(const uint4*)(spb + ((size_t)tg * NM + md) * 128 + ci8 * 16);
            *(uint4*)(lds + i * LROWB + s * MSTR + ci8 * 16) = val;
        }
    }
    __syncthreads();

    // ---- wave/lane decode ----
    const int hl = wv & 1;
    const int ct = (wv >> 1) & 1;
    const int jp = wv >> 2;                     // 0..1
    const int jlocal = (lane & 31) >> 4;
    const int mloc = lane & 15;
    const int hseg = lane >> 5;
    const int j = 2 * jp + jlocal;              // 0..3 (== LDS row index)

    int baseB[3], mv[3];
#pragma unroll
    for (int mc = 0; mc < 3; mc++) {
        int m = mc * 16 + mloc;                 // 0..47
        int meff = m > 39 ? 39 : m;
        baseB[mc] = j * LROWB + meff * MSTR + hseg * 16;
        mv[mc] = m;
    }

    v16f acc[3];
#pragma unroll
    for (int a = 0; a < 3; a++) acc[a] = (v16f)(0.0f);

    const uint4* wp = wfrag + (size_t)(ct * 2 + hl) * 64 + lane;
#pragma unroll
    for (int tap = 0; tap < 12; tap++) {
        const int kh = tap / 3, kw = tap % 3;
        const int bo = kh * LROWB + kw * (DW * MSTR);
#pragma unroll
        for (int cq = 0; cq < 4; cq++) {
            v8h A = *(const v8h*)(wp + (size_t)(tap * 4 + cq) * 256);
            v8h B0 = *(const v8h*)(lds + baseB[0] + bo + cq * 32);
            v8h B1 = *(const v8h*)(lds + baseB[1] + bo + cq * 32);
            v8h B2 = *(const v8h*)(lds + baseB[2] + bo + cq * 32);
            acc[0] = __builtin_amdgcn_mfma_f32_32x32x16_f16(A, B0, acc[0], 0, 0, 0);
            acc[1] = __builtin_amdgcn_mfma_f32_32x32x16_f16(A, B1, acc[1], 0, 0, 0);
            acc[2] = __builtin_amdgcn_mfma_f32_32x32x16_f16(A, B2, acc[2], 0, 0, 0);
        }
    }

    // ---- epilogue: raw plane writes (fold happens in LIF) ----
    float* uout = hl ? u_lo : u_hi;
    const int t = r + DH * (j0 + j);
    if (t < NT) {
#pragma unroll
        for (int mc = 0; mc < 3; mc++) {
            if (mv[mc] < NM) {
                float* base = uout + ((size_t)(b * NT + t) * NM + mv[mc]) * 64;
#pragma unroll
                for (int g = 0; g < 4; g++) {
                    int co = ct * 32 + 8 * g + 4 * hseg;  // D row map
                    float4 val;
                    val.x = acc[mc][4 * g + 0];
                    val.y = acc[mc][4 * g + 1];
                    val.z = acc[mc][4 * g + 2];
                    val.w = acc[mc][4 * g + 3];
                    *(float4*)(base + co) = val;
                }
            }
        }
    }
}

// ---- LIF over T: u = u_hi + u_lo/2048 -> compact f16 spikes, unroll-16 ----
__global__ void lif_spikes(const float* __restrict__ uh, const float* __restrict__ ul,
                           half_t* __restrict__ s2) {
    int tid = blockIdx.x * 256 + threadIdx.x;   // 81920
    int b = tid / 2560;
    int cm = tid % 2560;
    size_t base = (size_t)b * NT * 2560 + cm;
    const float* uph = uh + base;
    const float* upl = ul + base;
    half_t* sp = s2 + base;
    float v = 0.f;
    const float TAUc = 10.0f / 7.0f;
    const float invs = 1.0f / 2048.0f;
    for (int tb = 0; tb < 128; tb += 16) {
        float uu[16];
#pragma unroll
        for (int k = 0; k < 16; k++)
            uu[k] = uph[(size_t)(tb + k) * 2560] + upl[(size_t)(tb + k) * 2560] * invs;
#pragma unroll
        for (int k = 0; k < 16; k++) {
            v = v + (uu[k] - v) / TAUc;
            float s = (v >= 1.0f) ? 1.0f : 0.0f;
            sp[(size_t)(tb + k) * 2560] = (half_t)s;
            if (v >= 1.0f) v = 0.f;
        }
    }
    float uu = uph[(size_t)128 * 2560] + upl[(size_t)128 * 2560] * invs;
    v = v + (uu - v) / TAUc;
    sp[(size_t)128 * 2560] = (half_t)((v >= 1.0f) ? 1.0f : 0.0f);
}

// ---- LIF3: spike counts only (mean commutes with FC), unroll-16 ----
__global__ void lif_sum(const float* __restrict__ uh, const float* __restrict__ ul,
                        float* __restrict__ hsum) {
    int tid = blockIdx.x * 256 + threadIdx.x;   // 81920
    int b = tid / 2560;
    int cm = tid % 2560;                         // = m*64 + co
    int m = cm >> 6;
    int co = cm & 63;
    size_t base = (size_t)b * NT * 2560 + cm;
    const float* uph = uh + base;
    const float* upl = ul + base;
    float v = 0.f, cnt = 0.f;
    const float TAUc = 10.0f / 7.0f;
    const float invs = 1.0f / 2048.0f;
    for (int tb = 0; tb < 128; tb += 16) {
        float uu[16];
#pragma unroll
        for (int k = 0; k < 16; k++)
            uu[k] = uph[(size_t)(tb + k) * 2560] + upl[(size_t)(tb + k) * 2560] * invs;
#pragma unroll
        for (int k = 0; k < 16; k++) {
            v = v + (uu[k] - v) / TAUc;
            if (v >= 1.0f) { cnt += 1.0f; v = 0.f; }
        }
    }
    float uu = uph[(size_t)128 * 2560] + upl[(size_t)128 * 2560] * invs;
    v = v + (uu - v) / TAUc;
    if (v >= 1.0f) cnt += 1.0f;
    hsum[b * 2560 + co * NM + m] = cnt;          // feature index = c*40 + m
}

// ---- FC on counts: y[b,k] = bf[k] + (sum_cm cnt*wf[k,cm]) / 129 ----
__global__ void fc_out(const float* __restrict__ hsum, const float* __restrict__ wf,
                       const float* __restrict__ bfv, float* __restrict__ out) {
    int b = blockIdx.x;
    int tid = threadIdx.x;
    float p[12];
#pragma unroll
    for (int k = 0; k < 12; k++) p[k] = 0.0f;
    for (int cm = tid; cm < NC * NM; cm += 256) {
        float h = hsum[b * NC * NM + cm];
#pragma unroll
        for (int k = 0; k < 12; k++) p[k] += h * wf[k * (NC * NM) + cm];
    }
    __shared__ float red[12][4];
    int lane = tid & 63, w = tid >> 6;
#pragma unroll
    for (int k = 0; k < 12; k++) {
        float s = p[k];
#pragma unroll
        for (int off = 32; off > 0; off >>= 1) s += __shfl_down(s, off, 64);
        if (lane == 0) red[k][w] = s;
    }
    __syncthreads();
    if (tid < 12) {
        float s = red[tid][0] + red[tid][1] + red[tid][2] + red[tid][3];
        out[b * 12 + tid] = bfv[tid] + s / 129.0f;
    }
}

extern "C" void kernel_launch(void* const* d_in, const int* in_sizes, int n_in,
                              void* d_out, int out_size, void* d_ws, size_t ws_size,
                              hipStream_t stream) {
    const float* x  = (const float*)d_in[0];
    const float* w1 = (const float*)d_in[1];
    const float* w2 = (const float*)d_in[2];
    const float* w3 = (const float*)d_in[3];
    const float* wf = (const float*)d_in[4];
    const float* bf = (const float*)d_in[5];
    float* out = (float*)d_out;

    char* ws = (char*)d_ws;
    half_t* s1  = (half_t*)ws;                      // 21,135,360 B
    half_t* s2  = (half_t*)(ws + 21135360);         // 21,135,360 B
    float*  uh  = (float*)(ws + 42270720);          // 42,270,720 B
    float*  ul  = (float*)(ws + 84541440);          // 42,270,720 B
    uint4*  wf2 = (uint4*)(ws + 126812160);         // 196,608 B
    uint4*  wf3 = (uint4*)(ws + 127008768);         // 196,608 B
    float* hsum = (float*)(ws + 127205376);         // 327,680 B (end ~127.5 MB)

    prep_wfrag2<<<96, 256, 0, stream>>>(w2, w3, wf2, wf3);

    conv1_lif1<<<dim3(10, 32), 256, 0, stream>>>(x, w1, s1);

    // layer 2: EXT=46 -> LDS 43,792 B; NSTG = ceil(7*46*8/512) = 6
    convT<4, 6, 3, 3, 46, 2, 6><<<dim3(33, 32), 512, 43792, stream>>>(s1, wf2, uh, ul);
    lif_spikes<<<320, 256, 0, stream>>>(uh, ul, s2);

    // layer 3: EXT=58 -> LDS 55,216 B; NSTG = ceil(7*58*8/512) = 7
    convT<16, 24, 9, 9, 58, 4, 7><<<dim3(33, 32), 512, 55216, stream>>>(s2, wf3, uh, ul);
    lif_sum<<<320, 256, 0, stream>>>(uh, ul, hsum);

    fc_out<<<32, 256, 0, stream>>>(hsum, wf, bf, out);
}